// Round 2
// baseline (355.766 us; speedup 1.0000x reference)
//
#include <hip/hip_runtime.h>

#define N_ROWS 200000
#define D_IN   256
#define D_LAT  64
#define K_CL   100

#define TPB  256
#define KPT  25            // clusters per thread (4 threads/row)
#define GRPS (N_ROWS / 64) // 3125 row-groups of 64
#define CSTR 68            // padded LDS stride (floats), multiple of 4, !=0 mod 32

// ws layout: [0] double dec_acc | [1] double kl_acc | +16B float f[128] | +528B float cn2[128]

__device__ __forceinline__ float dot4(float4 a, float4 b, float acc) {
    acc = fmaf(a.x, b.x, acc); acc = fmaf(a.y, b.y, acc);
    acc = fmaf(a.z, b.z, acc); acc = fmaf(a.w, b.w, acc);
    return acc;
}

__global__ void k_cn2(const float* __restrict__ cen, float* __restrict__ cn2) {
    int k = blockIdx.x * blockDim.x + threadIdx.x;
    if (k < K_CL) {
        float s = 0.f;
        for (int d = 0; d < D_LAT; ++d) { float v = cen[k * D_LAT + d]; s = fmaf(v, v, s); }
        cn2[k] = s;
    }
}

__global__ void __launch_bounds__(256) k_dec(const float4* __restrict__ X,
                                             const float4* __restrict__ Dec,
                                             double* __restrict__ acc) {
    const int n4 = N_ROWS * D_IN / 4;
    int tid = blockIdx.x * blockDim.x + threadIdx.x;
    int stride = gridDim.x * blockDim.x;
    float local = 0.f;
    for (int i = tid; i < n4; i += stride) {
        float4 a = X[i], b = Dec[i];
        float dx = a.x - b.x, dy = a.y - b.y, dz = a.z - b.z, dw = a.w - b.w;
        local = fmaf(dx, dx, local); local = fmaf(dy, dy, local);
        local = fmaf(dz, dz, local); local = fmaf(dw, dw, local);
    }
    __shared__ float red[TPB];
    red[threadIdx.x] = local;
    __syncthreads();
    for (int off = TPB / 2; off > 0; off >>= 1) {
        if (threadIdx.x < off) red[threadIdx.x] += red[threadIdx.x + off];
        __syncthreads();
    }
    if (threadIdx.x == 0) atomicAdd(acc, (double)red[0]);
}

// ---- shared staging helpers (identical in both passes) ----
#define STAGE_CENTRES()                                                        \
    for (int i = tid; i < K_CL * 16; i += TPB) {                               \
        int k = i >> 4, c4 = i & 15;                                           \
        float4 v = reinterpret_cast<const float4*>(cen)[i];                    \
        float* dst = &c_s[k * CSTR + c4 * 4];                                  \
        dst[0] = v.x; dst[1] = v.y; dst[2] = v.z; dst[3] = v.w;                \
    }

#define STAGE_E(grp)                                                           \
    for (int i = tid; i < 64 * 16; i += TPB) {                                 \
        int r = i >> 4, c4 = i & 15;                                           \
        float4 v = reinterpret_cast<const float4*>(enc)[(grp) * 1024 + i];     \
        float* dst = &e_s[r * CSTR + c4 * 4];                                  \
        dst[0] = v.x; dst[1] = v.y; dst[2] = v.z; dst[3] = v.w;                \
    }

#define DO_DOTS()                                                              \
    float dot[KPT];                                                            \
    _Pragma("unroll")                                                          \
    for (int j = 0; j < KPT; ++j) dot[j] = 0.f;                                \
    float en2 = 0.f;                                                           \
    _Pragma("unroll 1")                                                        \
    for (int ch = 0; ch < 4; ++ch) {                                           \
        const float4* ep = reinterpret_cast<const float4*>(&e_s[rs * CSTR + ch * 16]); \
        float4 e0 = ep[0], e1 = ep[1], e2 = ep[2], e3 = ep[3];                 \
        en2 = dot4(e0, e0, en2); en2 = dot4(e1, e1, en2);                      \
        en2 = dot4(e2, e2, en2); en2 = dot4(e3, e3, en2);                      \
        _Pragma("unroll")                                                      \
        for (int j = 0; j < KPT; ++j) {                                        \
            const float4* cp = reinterpret_cast<const float4*>(&c_s[(kbase + j) * CSTR + ch * 16]); \
            float t = dot[j];                                                  \
            t = dot4(e0, cp[0], t); t = dot4(e1, cp[1], t);                    \
            t = dot4(e2, cp[2], t); t = dot4(e3, cp[3], t);                    \
            dot[j] = t;                                                        \
        }                                                                      \
    }

__global__ void __launch_bounds__(TPB) k_pass1(const float* __restrict__ enc,
                                               const float* __restrict__ cen,
                                               const float* __restrict__ cn2g,
                                               float* __restrict__ fg) {
    __shared__ float c_s[K_CL * CSTR];
    __shared__ float e_s[64 * CSTR];
    __shared__ float cn2_s[K_CL];
    __shared__ float f_s[K_CL];
    const int tid = threadIdx.x;
    STAGE_CENTRES();
    if (tid < K_CL) { cn2_s[tid] = cn2g[tid]; f_s[tid] = 0.f; }
    __syncthreads();
    const int sub = tid & 3, rs = tid >> 2, kbase = sub * KPT;
    float facc[KPT];
#pragma unroll
    for (int j = 0; j < KPT; ++j) facc[j] = 0.f;

    for (int grp = blockIdx.x; grp < GRPS; grp += gridDim.x) {
        __syncthreads();
        STAGE_E(grp);
        __syncthreads();
        DO_DOTS();
        float qu[KPT];
        float s = 0.f;
#pragma unroll
        for (int j = 0; j < KPT; ++j) {
            float d2 = en2 + cn2_s[kbase + j] - 2.f * dot[j];
            d2 = fmaxf(d2, 0.f);
            float q = 1.f / (1.f + d2);
            qu[j] = q; s += q;
        }
        s += __shfl_xor(s, 1); s += __shfl_xor(s, 2);
        float rsv = 1.f / s;
#pragma unroll
        for (int j = 0; j < KPT; ++j) facc[j] = fmaf(qu[j], rsv, facc[j]);
    }
    __syncthreads();
#pragma unroll
    for (int j = 0; j < KPT; ++j) atomicAdd(&f_s[kbase + j], facc[j]);
    __syncthreads();
    if (tid < K_CL) atomicAdd(&fg[tid], f_s[tid]);
}

__global__ void __launch_bounds__(TPB) k_pass2(const float* __restrict__ enc,
                                               const float* __restrict__ cen,
                                               const float* __restrict__ cn2g,
                                               const float* __restrict__ fg,
                                               double* __restrict__ kl_g) {
    __shared__ float c_s[K_CL * CSTR];
    __shared__ float e_s[64 * CSTR];
    __shared__ float cn2_s[K_CL];
    __shared__ float lf_s[K_CL];
    __shared__ float rf_s[K_CL];
    __shared__ float red[TPB];
    const int tid = threadIdx.x;
    STAGE_CENTRES();
    if (tid < K_CL) {
        cn2_s[tid] = cn2g[tid];
        float fv = fg[tid];
        lf_s[tid] = __logf(fv);
        rf_s[tid] = 1.f / fv;
    }
    __syncthreads();
    const int sub = tid & 3, rs = tid >> 2, kbase = sub * KPT;
    float kl_local = 0.f;

    for (int grp = blockIdx.x; grp < GRPS; grp += gridDim.x) {
        __syncthreads();
        STAGE_E(grp);
        __syncthreads();
        DO_DOTS();
        float qu[KPT];
        float s = 0.f;
#pragma unroll
        for (int j = 0; j < KPT; ++j) {
            float d2 = en2 + cn2_s[kbase + j] - 2.f * dot[j];
            d2 = fmaxf(d2, 0.f);
            float q = 1.f / (1.f + d2);
            qu[j] = q; s += q;
        }
        s += __shfl_xor(s, 1); s += __shfl_xor(s, 2);
        float rsv = 1.f / s;
        float t = 0.f, Ap = 0.f, Bp = 0.f;
#pragma unroll
        for (int j = 0; j < KPT; ++j) {
            float q = qu[j] * rsv;
            float pu = q * q * rf_s[kbase + j];
            t += pu;
            Ap = fmaf(pu, __logf(q), Ap);
            Bp = fmaf(pu, lf_s[kbase + j], Bp);
        }
        t  += __shfl_xor(t, 1);  t  += __shfl_xor(t, 2);
        Ap += __shfl_xor(Ap, 1); Ap += __shfl_xor(Ap, 2);
        Bp += __shfl_xor(Bp, 1); Bp += __shfl_xor(Bp, 2);
        if (sub == 0) kl_local += (Ap - Bp) / t - __logf(t);
    }
    __syncthreads();
    red[tid] = kl_local;
    __syncthreads();
    for (int off = TPB / 2; off > 0; off >>= 1) {
        if (tid < off) red[tid] += red[tid + off];
        __syncthreads();
    }
    if (tid == 0) atomicAdd(kl_g, (double)red[0]);
}

__global__ void k_final(const double* __restrict__ dec_acc,
                        const double* __restrict__ kl_acc,
                        float* __restrict__ out) {
    if (threadIdx.x == 0) {
        double d = dec_acc[0] / ((double)N_ROWS * (double)D_IN);
        double c = kl_acc[0] / (double)N_ROWS;
        out[0] = (float)(d + 1000.0 * c);
    }
}

extern "C" void kernel_launch(void* const* d_in, const int* in_sizes, int n_in,
                              void* d_out, int out_size, void* d_ws, size_t ws_size,
                              hipStream_t stream) {
    (void)in_sizes; (void)n_in; (void)out_size; (void)ws_size;
    const float* X   = (const float*)d_in[0];
    const float* enc = (const float*)d_in[1];
    const float* dec = (const float*)d_in[2];
    const float* cen = (const float*)d_in[3];
    float* out = (float*)d_out;

    double* dec_acc = (double*)d_ws;
    double* kl_acc  = dec_acc + 1;
    float*  fg      = (float*)((char*)d_ws + 16);
    float*  cn2     = fg + 128;

    hipMemsetAsync(d_ws, 0, 1056, stream);
    k_cn2<<<1, 128, 0, stream>>>(cen, cn2);
    k_dec<<<2048, TPB, 0, stream>>>((const float4*)X, (const float4*)dec, dec_acc);
    k_pass1<<<625, TPB, 0, stream>>>(enc, cen, cn2, fg);
    k_pass2<<<625, TPB, 0, stream>>>(enc, cen, cn2, fg, kl_acc);
    k_final<<<1, 64, 0, stream>>>(dec_acc, kl_acc, out);
}

// Round 3
// 186.634 us; speedup vs baseline: 1.9062x; 1.9062x over previous
//
#include <hip/hip_runtime.h>

#define N_ROWS 200000
#define D_IN   256
#define D_LAT  64
#define K_CL   100
#define NT     7            // 7 cluster tiles of 16 -> 112 (cols >=100 masked)
#define TPB    256
#define GRPS   3125         // row groups of 64 (4 waves x 16 rows)
#define NBLK   625

typedef __attribute__((ext_vector_type(8))) short bf16x8;
typedef __attribute__((ext_vector_type(4))) float f32x4;

__device__ __forceinline__ float rcpf(float x) { return __builtin_amdgcn_rcpf(x); }

__device__ __forceinline__ short f2bf(float f) {
    union { float f; unsigned u; } v; v.f = f;
    unsigned r = (v.u + 0x7fffu + ((v.u >> 16) & 1u)) >> 16;
    return (short)r;
}

// load 8 consecutive floats, convert to bf16x8, accumulate sum-of-squares
__device__ __forceinline__ void cvt8(const float* __restrict__ p, bf16x8& o, float& sq) {
    float4 a = *(const float4*)p;
    float4 b = *(const float4*)(p + 4);
    sq = fmaf(a.x, a.x, sq); sq = fmaf(a.y, a.y, sq);
    sq = fmaf(a.z, a.z, sq); sq = fmaf(a.w, a.w, sq);
    sq = fmaf(b.x, b.x, sq); sq = fmaf(b.y, b.y, sq);
    sq = fmaf(b.z, b.z, sq); sq = fmaf(b.w, b.w, sq);
    o[0] = f2bf(a.x); o[1] = f2bf(a.y); o[2] = f2bf(a.z); o[3] = f2bf(a.w);
    o[4] = f2bf(b.x); o[5] = f2bf(b.y); o[6] = f2bf(b.z); o[7] = f2bf(b.w);
}

__global__ void k_cn2(const float* __restrict__ cen, float* __restrict__ cn2) {
    int k = blockIdx.x * blockDim.x + threadIdx.x;
    if (k < K_CL) {
        float s = 0.f;
        for (int d = 0; d < D_LAT; ++d) { float v = cen[k * D_LAT + d]; s = fmaf(v, v, s); }
        cn2[k] = s;
    }
}

__global__ void __launch_bounds__(256) k_dec(const float4* __restrict__ X,
                                             const float4* __restrict__ Dec,
                                             double* __restrict__ acc) {
    const int n4 = N_ROWS * D_IN / 4;
    int tid = blockIdx.x * blockDim.x + threadIdx.x;
    int stride = gridDim.x * blockDim.x;
    float local = 0.f;
    for (int i = tid; i < n4; i += stride) {
        float4 a = X[i], b = Dec[i];
        float dx = a.x - b.x, dy = a.y - b.y, dz = a.z - b.z, dw = a.w - b.w;
        local = fmaf(dx, dx, local); local = fmaf(dy, dy, local);
        local = fmaf(dz, dz, local); local = fmaf(dw, dw, local);
    }
    __shared__ float red[TPB];
    red[threadIdx.x] = local;
    __syncthreads();
    for (int off = TPB / 2; off > 0; off >>= 1) {
        if (threadIdx.x < off) red[threadIdx.x] += red[threadIdx.x + off];
        __syncthreads();
    }
    if (threadIdx.x == 0) atomicAdd(acc, (double)red[0]);
}

// ---- shared prologue for both MFMA passes ----
// lane layout: c16 = lane&15 (A-row / B-col / C-col), g = lane>>4 (k-group / C-row-group)
#define MFMA_PROLOGUE()                                                        \
    const int tid = threadIdx.x;                                               \
    const int l   = tid & 63;                                                  \
    const int w   = tid >> 6;                                                  \
    const int c16 = l & 15;                                                    \
    const int g   = l >> 4;                                                    \
    bf16x8 bfrag[NT][2];                                                       \
    float  cn2v[NT];                                                           \
    _Pragma("unroll")                                                          \
    for (int t = 0; t < NT; ++t) {                                             \
        int col = t * 16 + c16;                                                \
        bool valid = col < K_CL;                                               \
        cn2v[t] = valid ? cn2g[col] : 0.f;                                     \
        _Pragma("unroll")                                                      \
        for (int kt = 0; kt < 2; ++kt) {                                       \
            bf16x8 bf;                                                         \
            if (valid) {                                                       \
                float dummy = 0.f;                                             \
                cvt8(cen + col * D_LAT + kt * 32 + g * 8, bf, dummy);          \
            } else {                                                           \
                _Pragma("unroll")                                              \
                for (int i = 0; i < 8; ++i) bf[i] = 0;                         \
            }                                                                  \
            bfrag[t][kt] = bf;                                                 \
        }                                                                      \
    }                                                                          \
    const bool v6 = (c16 < 4); /* tile 6: cols 96..111, valid < 100 */

// per-group: load A frags, compute acc[NT] (dot), en2r[4], qv[NT][4], rs[4]
#define MFMA_GROUP_BODY()                                                      \
    const int rowbase = grp * 64 + w * 16;                                     \
    const float* arow = enc + (size_t)(rowbase + c16) * D_LAT;                 \
    float en2p = 0.f;                                                          \
    bf16x8 afrag[2];                                                           \
    cvt8(arow + g * 8, afrag[0], en2p);                                        \
    cvt8(arow + 32 + g * 8, afrag[1], en2p);                                   \
    en2p += __shfl_xor(en2p, 16);                                              \
    en2p += __shfl_xor(en2p, 32);                                              \
    f32x4 acc[NT];                                                             \
    _Pragma("unroll")                                                          \
    for (int t = 0; t < NT; ++t) {                                             \
        acc[t][0] = 0.f; acc[t][1] = 0.f; acc[t][2] = 0.f; acc[t][3] = 0.f;    \
    }                                                                          \
    _Pragma("unroll")                                                          \
    for (int kt = 0; kt < 2; ++kt) {                                           \
        _Pragma("unroll")                                                      \
        for (int t = 0; t < NT; ++t)                                           \
            acc[t] = __builtin_amdgcn_mfma_f32_16x16x32_bf16(                  \
                afrag[kt], bfrag[t][kt], acc[t], 0, 0, 0);                     \
    }                                                                          \
    float en2r[4];                                                             \
    _Pragma("unroll")                                                          \
    for (int r = 0; r < 4; ++r) en2r[r] = __shfl(en2p, g * 4 + r);             \
    float qv[NT][4];                                                           \
    float rs[4] = {0.f, 0.f, 0.f, 0.f};                                        \
    _Pragma("unroll")                                                          \
    for (int t = 0; t < NT; ++t) {                                             \
        _Pragma("unroll")                                                      \
        for (int r = 0; r < 4; ++r) {                                          \
            float d2 = en2r[r] + cn2v[t] - 2.f * acc[t][r];                    \
            float q = rcpf(1.f + fmaxf(d2, 0.f));                              \
            if (t == 6 && !v6) q = 0.f;                                        \
            qv[t][r] = q; rs[r] += q;                                          \
        }                                                                      \
    }                                                                          \
    _Pragma("unroll")                                                          \
    for (int r = 0; r < 4; ++r) {                                              \
        rs[r] += __shfl_xor(rs[r], 1);                                         \
        rs[r] += __shfl_xor(rs[r], 2);                                         \
        rs[r] += __shfl_xor(rs[r], 4);                                         \
        rs[r] += __shfl_xor(rs[r], 8);                                         \
        rs[r] = rcpf(rs[r]);                                                   \
    }

__global__ void __launch_bounds__(TPB) k_pass1(const float* __restrict__ enc,
                                               const float* __restrict__ cen,
                                               const float* __restrict__ cn2g,
                                               float* __restrict__ fg) {
    MFMA_PROLOGUE();
    float facc[NT];
#pragma unroll
    for (int t = 0; t < NT; ++t) facc[t] = 0.f;

    for (int grp = blockIdx.x; grp < GRPS; grp += gridDim.x) {
        MFMA_GROUP_BODY();
#pragma unroll
        for (int t = 0; t < NT; ++t) {
            float a = 0.f;
#pragma unroll
            for (int r = 0; r < 4; ++r) a = fmaf(qv[t][r], rs[r], a);
            facc[t] += a;
        }
    }
    __shared__ float f_s[K_CL];
    for (int i = tid; i < K_CL; i += TPB) f_s[i] = 0.f;
    __syncthreads();
#pragma unroll
    for (int t = 0; t < NT; ++t) {
        float a = facc[t];
        a += __shfl_xor(a, 16);
        a += __shfl_xor(a, 32);
        int col = t * 16 + c16;
        if (g == 0 && col < K_CL) atomicAdd(&f_s[col], a);
    }
    __syncthreads();
    for (int i = tid; i < K_CL; i += TPB) atomicAdd(&fg[i], f_s[i]);
}

__global__ void __launch_bounds__(TPB) k_pass2(const float* __restrict__ enc,
                                               const float* __restrict__ cen,
                                               const float* __restrict__ cn2g,
                                               const float* __restrict__ fg,
                                               double* __restrict__ kl_g) {
    MFMA_PROLOGUE();
    float lfv[NT], rfv[NT];
#pragma unroll
    for (int t = 0; t < NT; ++t) {
        int col = t * 16 + c16;
        if (col < K_CL) {
            float fv = fg[col];
            lfv[t] = __logf(fv);
            rfv[t] = rcpf(fv);
        } else { lfv[t] = 0.f; rfv[t] = 0.f; }
    }
    float kl_local = 0.f;

    for (int grp = blockIdx.x; grp < GRPS; grp += gridDim.x) {
        MFMA_GROUP_BODY();
        float tac[4] = {0.f, 0.f, 0.f, 0.f};
        float Ap[4]  = {0.f, 0.f, 0.f, 0.f};
        float Bp[4]  = {0.f, 0.f, 0.f, 0.f};
#pragma unroll
        for (int t = 0; t < NT; ++t) {
#pragma unroll
            for (int r = 0; r < 4; ++r) {
                if (t == 6 && !v6) continue;      // masked col: q==0, avoid log(0)
                float q = qv[t][r] * rs[r];
                float pu = q * q * rfv[t];
                tac[r] += pu;
                Ap[r] = fmaf(pu, __logf(q), Ap[r]);
                Bp[r] = fmaf(pu, lfv[t], Bp[r]);
            }
        }
#pragma unroll
        for (int r = 0; r < 4; ++r) {
            tac[r] += __shfl_xor(tac[r], 1); tac[r] += __shfl_xor(tac[r], 2);
            tac[r] += __shfl_xor(tac[r], 4); tac[r] += __shfl_xor(tac[r], 8);
            Ap[r]  += __shfl_xor(Ap[r], 1);  Ap[r]  += __shfl_xor(Ap[r], 2);
            Ap[r]  += __shfl_xor(Ap[r], 4);  Ap[r]  += __shfl_xor(Ap[r], 8);
            Bp[r]  += __shfl_xor(Bp[r], 1);  Bp[r]  += __shfl_xor(Bp[r], 2);
            Bp[r]  += __shfl_xor(Bp[r], 4);  Bp[r]  += __shfl_xor(Bp[r], 8);
        }
        if (c16 == 0) {
#pragma unroll
            for (int r = 0; r < 4; ++r)
                kl_local += (Ap[r] - Bp[r]) * rcpf(tac[r]) - __logf(tac[r]);
        }
    }
    __shared__ float red[TPB];
    red[tid] = kl_local;
    __syncthreads();
    for (int off = TPB / 2; off > 0; off >>= 1) {
        if (tid < off) red[tid] += red[tid + off];
        __syncthreads();
    }
    if (tid == 0) atomicAdd(kl_g, (double)red[0]);
}

__global__ void k_final(const double* __restrict__ dec_acc,
                        const double* __restrict__ kl_acc,
                        float* __restrict__ out) {
    if (threadIdx.x == 0) {
        double d = dec_acc[0] / ((double)N_ROWS * (double)D_IN);
        double c = kl_acc[0] / (double)N_ROWS;
        out[0] = (float)(d + 1000.0 * c);
    }
}

extern "C" void kernel_launch(void* const* d_in, const int* in_sizes, int n_in,
                              void* d_out, int out_size, void* d_ws, size_t ws_size,
                              hipStream_t stream) {
    (void)in_sizes; (void)n_in; (void)out_size; (void)ws_size;
    const float* X   = (const float*)d_in[0];
    const float* enc = (const float*)d_in[1];
    const float* dec = (const float*)d_in[2];
    const float* cen = (const float*)d_in[3];
    float* out = (float*)d_out;

    double* dec_acc = (double*)d_ws;
    double* kl_acc  = dec_acc + 1;
    float*  fg      = (float*)((char*)d_ws + 16);
    float*  cn2     = fg + 128;

    hipMemsetAsync(d_ws, 0, 1056, stream);
    k_cn2<<<1, 128, 0, stream>>>(cen, cn2);
    k_dec<<<2048, TPB, 0, stream>>>((const float4*)X, (const float4*)dec, dec_acc);
    k_pass1<<<NBLK, TPB, 0, stream>>>(enc, cen, cn2, fg);
    k_pass2<<<NBLK, TPB, 0, stream>>>(enc, cen, cn2, fg, kl_acc);
    k_final<<<1, 64, 0, stream>>>(dec_acc, kl_acc, out);
}

// Round 4
// 169.018 us; speedup vs baseline: 2.1049x; 1.1042x over previous
//
#include <hip/hip_runtime.h>

#define N_ROWS 200000
#define D_IN   256
#define D_LAT  64
#define K_CL   100
#define NT     7            // 7 cluster tiles of 16 -> 112 (cols >=100 masked)
#define TPB    256
#define GRPS   3125         // row groups of 64 (4 waves x 16 rows)
#define NBLK_P1  625
#define NBLK_DEC 2000
#define NBLK_P2  1250
#define DEC_THREADS (NBLK_DEC * TPB)              // 512000
// 200000*256/4 = 12.8e6 float4-pairs = DEC_THREADS * 25

typedef __attribute__((ext_vector_type(8))) short bf16x8;
typedef __attribute__((ext_vector_type(4))) float f32x4;

__device__ __forceinline__ float rcpf(float x) { return __builtin_amdgcn_rcpf(x); }

__device__ __forceinline__ short f2bf(float f) {
    union { float f; unsigned u; } v; v.f = f;
    unsigned r = (v.u + 0x7fffu + ((v.u >> 16) & 1u)) >> 16;
    return (short)r;
}

// load 8 consecutive floats, convert to bf16x8, accumulate sum-of-squares (fp32)
__device__ __forceinline__ void cvt8(const float* __restrict__ p, bf16x8& o, float& sq) {
    float4 a = *(const float4*)p;
    float4 b = *(const float4*)(p + 4);
    sq = fmaf(a.x, a.x, sq); sq = fmaf(a.y, a.y, sq);
    sq = fmaf(a.z, a.z, sq); sq = fmaf(a.w, a.w, sq);
    sq = fmaf(b.x, b.x, sq); sq = fmaf(b.y, b.y, sq);
    sq = fmaf(b.z, b.z, sq); sq = fmaf(b.w, b.w, sq);
    o[0] = f2bf(a.x); o[1] = f2bf(a.y); o[2] = f2bf(a.z); o[3] = f2bf(a.w);
    o[4] = f2bf(b.x); o[5] = f2bf(b.y); o[6] = f2bf(b.z); o[7] = f2bf(b.w);
}

// ---- MFMA prologue: B fragments + ||c||^2 computed in-register (no cn2 kernel) ----
// lane layout: c16 = lane&15 (A-row / B-col / C-col), g = lane>>4 (k-group / C-row-group)
#define MFMA_PROLOGUE()                                                        \
    const int tid = threadIdx.x;                                               \
    const int l   = tid & 63;                                                  \
    const int w   = tid >> 6;                                                  \
    const int c16 = l & 15;                                                    \
    const int g   = l >> 4;                                                    \
    bf16x8 bfrag[NT][2];                                                       \
    float  cn2v[NT];                                                           \
    _Pragma("unroll")                                                          \
    for (int t = 0; t < NT; ++t) {                                             \
        int col = t * 16 + c16;                                                \
        bool valid = col < K_CL;                                               \
        float sq = 0.f;                                                        \
        _Pragma("unroll")                                                      \
        for (int kt = 0; kt < 2; ++kt) {                                       \
            bf16x8 bf;                                                         \
            if (valid) {                                                       \
                cvt8(cen + col * D_LAT + kt * 32 + g * 8, bf, sq);             \
            } else {                                                           \
                _Pragma("unroll")                                              \
                for (int i = 0; i < 8; ++i) bf[i] = 0;                         \
            }                                                                  \
            bfrag[t][kt] = bf;                                                 \
        }                                                                      \
        sq += __shfl_xor(sq, 16);                                              \
        sq += __shfl_xor(sq, 32);                                              \
        cn2v[t] = sq;                                                          \
    }                                                                          \
    const bool v6 = (c16 < 4); /* tile 6: cols 96..111, valid < 100 */

// per-group: load A frags, MFMA dot, en2r[4], qv[NT][4], rs[4]
#define MFMA_GROUP_BODY()                                                      \
    const int rowbase = grp * 64 + w * 16;                                     \
    const float* arow = enc + (size_t)(rowbase + c16) * D_LAT;                 \
    float en2p = 0.f;                                                          \
    bf16x8 afrag[2];                                                           \
    cvt8(arow + g * 8, afrag[0], en2p);                                        \
    cvt8(arow + 32 + g * 8, afrag[1], en2p);                                   \
    en2p += __shfl_xor(en2p, 16);                                              \
    en2p += __shfl_xor(en2p, 32);                                              \
    f32x4 acc[NT];                                                             \
    _Pragma("unroll")                                                          \
    for (int t = 0; t < NT; ++t) {                                             \
        acc[t][0] = 0.f; acc[t][1] = 0.f; acc[t][2] = 0.f; acc[t][3] = 0.f;    \
    }                                                                          \
    _Pragma("unroll")                                                          \
    for (int kt = 0; kt < 2; ++kt) {                                           \
        _Pragma("unroll")                                                      \
        for (int t = 0; t < NT; ++t)                                           \
            acc[t] = __builtin_amdgcn_mfma_f32_16x16x32_bf16(                  \
                afrag[kt], bfrag[t][kt], acc[t], 0, 0, 0);                     \
    }                                                                          \
    float en2r[4];                                                             \
    _Pragma("unroll")                                                          \
    for (int r = 0; r < 4; ++r) en2r[r] = __shfl(en2p, g * 4 + r);             \
    float qv[NT][4];                                                           \
    float rs[4] = {0.f, 0.f, 0.f, 0.f};                                        \
    _Pragma("unroll")                                                          \
    for (int t = 0; t < NT; ++t) {                                             \
        _Pragma("unroll")                                                      \
        for (int r = 0; r < 4; ++r) {                                          \
            float d2 = en2r[r] + cn2v[t] - 2.f * acc[t][r];                    \
            float q = rcpf(1.f + fmaxf(d2, 0.f));                              \
            if (t == 6 && !v6) q = 0.f;                                        \
            qv[t][r] = q; rs[r] += q;                                          \
        }                                                                      \
    }                                                                          \
    _Pragma("unroll")                                                          \
    for (int r = 0; r < 4; ++r) {                                              \
        rs[r] += __shfl_xor(rs[r], 1);                                         \
        rs[r] += __shfl_xor(rs[r], 2);                                         \
        rs[r] += __shfl_xor(rs[r], 4);                                         \
        rs[r] += __shfl_xor(rs[r], 8);                                         \
        rs[r] = rcpf(rs[r]);                                                   \
    }

// ---- decoder-loss streaming body: 25 float4-pairs/thread, 5x5 unroll, nt loads ----
__device__ __forceinline__ void dec_body(const f32x4* __restrict__ X,
                                         const f32x4* __restrict__ Dec,
                                         double* __restrict__ acc) {
    const int bid = blockIdx.x - NBLK_P1;
    int idx = bid * TPB + threadIdx.x;
    float local = 0.f;
#pragma unroll 1
    for (int o = 0; o < 5; ++o) {
        f32x4 a[5], b[5];
#pragma unroll
        for (int u = 0; u < 5; ++u) {
            a[u] = __builtin_nontemporal_load(X + idx + u * DEC_THREADS);
            b[u] = __builtin_nontemporal_load(Dec + idx + u * DEC_THREADS);
        }
#pragma unroll
        for (int u = 0; u < 5; ++u) {
            f32x4 d = a[u] - b[u];
            local = fmaf(d.x, d.x, local); local = fmaf(d.y, d.y, local);
            local = fmaf(d.z, d.z, local); local = fmaf(d.w, d.w, local);
        }
        idx += 5 * DEC_THREADS;
    }
    __shared__ float red[TPB];
    red[threadIdx.x] = local;
    __syncthreads();
    for (int off = TPB / 2; off > 0; off >>= 1) {
        if (threadIdx.x < off) red[threadIdx.x] += red[threadIdx.x + off];
        __syncthreads();
    }
    if (threadIdx.x == 0) atomicAdd(acc, (double)red[0]);
}

// ---- fused: blocks [0,625) = pass1 (MFMA, f accumulation); [625,2625) = dec stream ----
__global__ void __launch_bounds__(TPB) k_fused(const f32x4* __restrict__ X,
                                               const f32x4* __restrict__ Xdec,
                                               const float* __restrict__ enc,
                                               const float* __restrict__ cen,
                                               double* __restrict__ dec_acc,
                                               float* __restrict__ fg) {
    if (blockIdx.x >= NBLK_P1) {
        dec_body(X, Xdec, dec_acc);
        return;
    }
    MFMA_PROLOGUE();
    float facc[NT];
#pragma unroll
    for (int t = 0; t < NT; ++t) facc[t] = 0.f;

    for (int grp = blockIdx.x; grp < GRPS; grp += NBLK_P1) {
        MFMA_GROUP_BODY();
#pragma unroll
        for (int t = 0; t < NT; ++t) {
            float a = 0.f;
#pragma unroll
            for (int r = 0; r < 4; ++r) a = fmaf(qv[t][r], rs[r], a);
            facc[t] += a;
        }
    }
    __shared__ float f_s[K_CL];
    for (int i = tid; i < K_CL; i += TPB) f_s[i] = 0.f;
    __syncthreads();
#pragma unroll
    for (int t = 0; t < NT; ++t) {
        float a = facc[t];
        a += __shfl_xor(a, 16);
        a += __shfl_xor(a, 32);
        int col = t * 16 + c16;
        if (g == 0 && col < K_CL) atomicAdd(&f_s[col], a);
    }
    __syncthreads();
    for (int i = tid; i < K_CL; i += TPB) atomicAdd(&fg[i], f_s[i]);
}

__global__ void __launch_bounds__(TPB) k_pass2(const float* __restrict__ enc,
                                               const float* __restrict__ cen,
                                               const float* __restrict__ fg,
                                               double* __restrict__ kl_g) {
    MFMA_PROLOGUE();
    float lfv[NT], rfv[NT];
#pragma unroll
    for (int t = 0; t < NT; ++t) {
        int col = t * 16 + c16;
        if (col < K_CL) {
            float fv = fg[col];
            lfv[t] = __logf(fv);
            rfv[t] = rcpf(fv);
        } else { lfv[t] = 0.f; rfv[t] = 0.f; }
    }
    float kl_local = 0.f;

    for (int grp = blockIdx.x; grp < GRPS; grp += NBLK_P2) {
        MFMA_GROUP_BODY();
        float tac[4] = {0.f, 0.f, 0.f, 0.f};
        float Ap[4]  = {0.f, 0.f, 0.f, 0.f};
        float Bp[4]  = {0.f, 0.f, 0.f, 0.f};
#pragma unroll
        for (int t = 0; t < NT; ++t) {
#pragma unroll
            for (int r = 0; r < 4; ++r) {
                if (t == 6 && !v6) continue;      // masked col: q==0, avoid log(0)
                float q = qv[t][r] * rs[r];
                float pu = q * q * rfv[t];
                tac[r] += pu;
                Ap[r] = fmaf(pu, __logf(q), Ap[r]);
                Bp[r] = fmaf(pu, lfv[t], Bp[r]);
            }
        }
#pragma unroll
        for (int r = 0; r < 4; ++r) {
            tac[r] += __shfl_xor(tac[r], 1); tac[r] += __shfl_xor(tac[r], 2);
            tac[r] += __shfl_xor(tac[r], 4); tac[r] += __shfl_xor(tac[r], 8);
            Ap[r]  += __shfl_xor(Ap[r], 1);  Ap[r]  += __shfl_xor(Ap[r], 2);
            Ap[r]  += __shfl_xor(Ap[r], 4);  Ap[r]  += __shfl_xor(Ap[r], 8);
            Bp[r]  += __shfl_xor(Bp[r], 1);  Bp[r]  += __shfl_xor(Bp[r], 2);
            Bp[r]  += __shfl_xor(Bp[r], 4);  Bp[r]  += __shfl_xor(Bp[r], 8);
        }
        if (c16 == 0) {
#pragma unroll
            for (int r = 0; r < 4; ++r)
                kl_local += (Ap[r] - Bp[r]) * rcpf(tac[r]) - __logf(tac[r]);
        }
    }
    __shared__ float red[TPB];
    red[tid] = kl_local;
    __syncthreads();
    for (int off = TPB / 2; off > 0; off >>= 1) {
        if (tid < off) red[tid] += red[tid + off];
        __syncthreads();
    }
    if (tid == 0) atomicAdd(kl_g, (double)red[0]);
}

__global__ void k_final(const double* __restrict__ dec_acc,
                        const double* __restrict__ kl_acc,
                        float* __restrict__ out) {
    if (threadIdx.x == 0) {
        double d = dec_acc[0] / ((double)N_ROWS * (double)D_IN);
        double c = kl_acc[0] / (double)N_ROWS;
        out[0] = (float)(d + 1000.0 * c);
    }
}

extern "C" void kernel_launch(void* const* d_in, const int* in_sizes, int n_in,
                              void* d_out, int out_size, void* d_ws, size_t ws_size,
                              hipStream_t stream) {
    (void)in_sizes; (void)n_in; (void)out_size; (void)ws_size;
    const float* X   = (const float*)d_in[0];
    const float* enc = (const float*)d_in[1];
    const float* dec = (const float*)d_in[2];
    const float* cen = (const float*)d_in[3];
    float* out = (float*)d_out;

    double* dec_acc = (double*)d_ws;
    double* kl_acc  = dec_acc + 1;
    float*  fg      = (float*)((char*)d_ws + 16);

    hipMemsetAsync(d_ws, 0, 544, stream);
    k_fused<<<NBLK_P1 + NBLK_DEC, TPB, 0, stream>>>(
        (const f32x4*)X, (const f32x4*)dec, enc, cen, dec_acc, fg);
    k_pass2<<<NBLK_P2, TPB, 0, stream>>>(enc, cen, fg, kl_acc);
    k_final<<<1, 64, 0, stream>>>(dec_acc, kl_acc, out);
}